// Round 1
// baseline (198.902 us; speedup 1.0000x reference)
//
#include <hip/hip_runtime.h>
#include <math.h>

// B=32768 rows, C=1000 classes, K=10 attack indices per row.
// One wave (64 lanes) per row; 4 waves per 256-thread block.
// Memory-bound: 131 MB read -> ~21us floor at 6.3 TB/s.

#define NC 1000
#define NK 10
#define NV4 250   // float4s per row (1000/4); row stride 4000B is 16B-aligned

__global__ __launch_bounds__(256) void boiler_loss_kernel(
    const float* __restrict__ y_pred,
    const int*   __restrict__ y_att,
    float*       __restrict__ out,
    int B)
{
    const int wave = threadIdx.x >> 6;   // 0..3
    const int lane = threadIdx.x & 63;
    const int row  = blockIdx.x * 4 + wave;
    if (row >= B) return;

    const float* __restrict__ xrow = y_pred + (size_t)row * NC;
    const int*   __restrict__ arow = y_att + (size_t)row * NK;

    // ---- attack indices: lanes 0..9 load, broadcast to all lanes ----
    int aidx = (lane < NK) ? arow[lane] : -1;
    int att[NK];
    #pragma unroll
    for (int j = 0; j < NK; ++j) att[j] = __shfl(aidx, j, 64);

    // gather attack logits (same cache lines as the streaming load -> L1/L2 hit)
    float aval = (lane < NK) ? xrow[aidx] : 0.0f;

    // ---- main streaming load: 250 float4s, lane + 64*k ----
    float v[16];
    const float4* __restrict__ xv = (const float4*)xrow;
    #pragma unroll
    for (int k = 0; k < 4; ++k) {
        const int i4 = lane + 64 * k;
        float4 f;
        if (i4 < NV4) f = xv[i4];
        else f = make_float4(-INFINITY, -INFINITY, -INFINITY, -INFINITY);
        v[4*k+0] = f.x; v[4*k+1] = f.y; v[4*k+2] = f.z; v[4*k+3] = f.w;
    }

    // ---- per-lane max (all) and max (non-attack) ----
    float mAll = -INFINITY, mNA = -INFINITY;
    #pragma unroll
    for (int k = 0; k < 4; ++k) {
        const int base = (lane + 64 * k) * 4;
        #pragma unroll
        for (int t = 0; t < 4; ++t) {
            const float f = v[4*k + t];
            mAll = fmaxf(mAll, f);
            const int gi = base + t;
            bool isAtt = false;
            #pragma unroll
            for (int j = 0; j < NK; ++j) isAtt |= (gi == att[j]);
            if (!isAtt) mNA = fmaxf(mNA, f);
        }
    }
    // butterfly reduce across the wave (all lanes end with result)
    #pragma unroll
    for (int off = 32; off > 0; off >>= 1) {
        mAll = fmaxf(mAll, __shfl_xor(mAll, off, 64));
        mNA  = fmaxf(mNA,  __shfl_xor(mNA,  off, 64));
    }

    // ---- sum of exp(x - m); padding lanes contribute exp(-inf)=0 ----
    float s = 0.0f;
    #pragma unroll
    for (int k = 0; k < 16; ++k) s += expf(v[k] - mAll);
    #pragma unroll
    for (int off = 32; off > 0; off >>= 1) s += __shfl_xor(s, off, 64);

    // ---- attack probs on lanes 0..9 (true division, matching jax softmax) ----
    float pj = 0.0f;
    if (lane < NK) pj = expf(aval - mAll) / s;

    // collect the 10 probs on every lane (cheap), epilogue on lane 0
    float p[NK];
    #pragma unroll
    for (int j = 0; j < NK; ++j) p[j] = __shfl(pj, j, 64);

    if (lane == 0) {
        const float pNA = expf(mNA - mAll) / s;   // max prob over complement
        float pmin = p[0];
        #pragma unroll
        for (int j = 1; j < NK; ++j) pmin = fminf(pmin, p[j]);
        const float macro_loss = pNA - pmin;

        // generalized mean p=9 over (5 + 5*diff), done in double like torch/jax
        double acc9 = 0.0;
        #pragma unroll
        for (int j = 0; j < NK - 1; ++j) {
            const float d  = p[j+1] - p[j];
            const float sv = 5.0f + 5.0f * d;          // float32, like reference
            const double xd = (double)sv;
            const double x2 = xd * xd;
            const double x4 = x2 * x2;
            const double x8 = x4 * x4;
            acc9 += x8 * xd;                           // x^9
        }
        const double gm9 = pow(acc9 / 9.0, 1.0 / 9.0);
        const float sorting = ((float)gm9 - 5.0f) / 5.0f;

        // generalized mean p=10 over {5+5*macro, 5+5*sorting}
        const float c0 = 5.0f + 5.0f * macro_loss;
        const float c1 = 5.0f + 5.0f * sorting;
        const double d0 = (double)c0, d1 = (double)c1;
        const double d0_2 = d0 * d0, d0_4 = d0_2 * d0_2, d0_8 = d0_4 * d0_4;
        const double d1_2 = d1 * d1, d1_4 = d1_2 * d1_2, d1_8 = d1_4 * d1_4;
        const double m10  = (d0_8 * d0_2 + d1_8 * d1_2) * 0.5;
        const double gm10 = pow(m10, 0.1);

        out[row] = ((float)gm10 - 5.0f) / 5.0f;
    }
}

extern "C" void kernel_launch(void* const* d_in, const int* in_sizes, int n_in,
                              void* d_out, int out_size, void* d_ws, size_t ws_size,
                              hipStream_t stream) {
    const float* y_pred = (const float*)d_in[0];
    const int*   y_att  = (const int*)d_in[1];
    float* out = (float*)d_out;
    const int B = in_sizes[0] / NC;          // 32768
    const int blocks = (B + 3) / 4;          // 4 rows (waves) per block
    boiler_loss_kernel<<<blocks, 256, 0, stream>>>(y_pred, y_att, out, B);
}

// Round 2
// 183.915 us; speedup vs baseline: 1.0815x; 1.0815x over previous
//
#include <hip/hip_runtime.h>
#include <math.h>

// B=32768 rows, C=1000 classes, K=10 attack indices per row.
// One wave (64 lanes) per row; 4 waves per 256-thread block.
// Memory-bound target: 131 MB read -> ~21us floor at 6.3 TB/s.
//
// Key tricks vs naive:
//  - softmax never materialized: only row max, sum(exp), 10 gathered logits,
//    and max over the non-attack complement are needed (exp is monotone).
//  - attack exclusion via per-lane 16-bit ownership mask (10 compares/lane),
//    not per-element index compares (160/lane).
//  - fp32-only epilogue: x^(1/p) via exp2f(log2f(x)/p); abs error ~1e-5,
//    threshold is 1.27e-3.

#define NC 1000
#define NK 10
#define NV4 250   // float4s per row; row stride 4000B is 16B-aligned
#define L2E 1.44269504088896340736f

__global__ __launch_bounds__(256) void boiler_loss_kernel(
    const float* __restrict__ y_pred,
    const int*   __restrict__ y_att,
    float*       __restrict__ out,
    int B)
{
    const int wave = threadIdx.x >> 6;   // 0..3
    const int lane = threadIdx.x & 63;
    const int row  = blockIdx.x * 4 + wave;
    if (row >= B) return;

    const float* __restrict__ xrow = y_pred + (size_t)row * NC;
    const int*   __restrict__ arow = y_att + (size_t)row * NK;

    // ---- attack indices: lanes 0..9 load, broadcast to all lanes ----
    int aidx = (lane < NK) ? arow[lane] : 0;
    int att[NK];
    #pragma unroll
    for (int j = 0; j < NK; ++j) att[j] = __shfl(aidx, j, 64);

    // gather the 10 attack logits (cache-hit; junk on lanes >= 10)
    const float aval = xrow[aidx];

    // ---- main streaming load: 250 float4s, lane + 64*k ----
    float v[16];
    const float4* __restrict__ xv = (const float4*)xrow;
    #pragma unroll
    for (int k = 0; k < 4; ++k) {
        const int i4 = lane + 64 * k;
        float4 f;
        if (i4 < NV4) f = xv[i4];
        else f = make_float4(-INFINITY, -INFINITY, -INFINITY, -INFINITY);
        v[4*k+0] = f.x; v[4*k+1] = f.y; v[4*k+2] = f.z; v[4*k+3] = f.w;
    }

    // ---- ownership mask: which of MY 16 regs hold attack elements ----
    // element gi lives at vec i4=gi>>2 -> lane=i4&63, reg=((i4>>6)<<2)|(gi&3)
    unsigned bits = 0u;
    #pragma unroll
    for (int j = 0; j < NK; ++j) {
        const int i4a   = att[j] >> 2;
        const int owner = i4a & 63;
        const int reg   = ((i4a >> 6) << 2) | (att[j] & 3);
        bits |= (owner == lane) ? (1u << reg) : 0u;
    }

    // ---- per-lane max (all) and max (non-attack) ----
    float mAll = -INFINITY, mNA = -INFINITY;
    #pragma unroll
    for (int r = 0; r < 16; ++r) {
        const float f = v[r];
        mAll = fmaxf(mAll, f);
        const float g = ((bits >> r) & 1u) ? -INFINITY : f;
        mNA = fmaxf(mNA, g);
    }
    #pragma unroll
    for (int off = 32; off > 0; off >>= 1) {
        mAll = fmaxf(mAll, __shfl_xor(mAll, off, 64));
        mNA  = fmaxf(mNA,  __shfl_xor(mNA,  off, 64));
    }

    // ---- sum of 2^((x-m)*log2e); padding lanes give exp2(-inf)=0 ----
    const float mscale = -mAll * L2E;
    float s = 0.0f;
    #pragma unroll
    for (int r = 0; r < 16; ++r) s += exp2f(fmaf(v[r], L2E, mscale));
    #pragma unroll
    for (int off = 32; off > 0; off >>= 1) s += __shfl_xor(s, off, 64);

    const float rs = 1.0f / s;

    // attack probs (valid on lanes 0..9), broadcast to all
    const float pjl = exp2f(fmaf(aval, L2E, mscale)) * rs;
    float p[NK];
    #pragma unroll
    for (int j = 0; j < NK; ++j) p[j] = __shfl(pjl, j, 64);

    if (lane == 0) {
        const float pNA = exp2f(fmaf(mNA, L2E, mscale)) * rs; // max prob, complement
        float pmin = p[0];
        #pragma unroll
        for (int j = 1; j < NK; ++j) pmin = fminf(pmin, p[j]);
        const float macro_loss = pNA - pmin;

        // generalized mean p=9 over (5 + 5*diff), fp32
        float acc9 = 0.0f;
        #pragma unroll
        for (int j = 0; j < NK - 1; ++j) {
            const float sv = fmaf(5.0f, p[j+1] - p[j], 5.0f);   // in [0,10]
            const float x2 = sv * sv;
            const float x4 = x2 * x2;
            const float x8 = x4 * x4;
            acc9 = fmaf(x8, sv, acc9);                          // += sv^9
        }
        const float gm9 = exp2f(log2f(acc9 * (1.0f / 9.0f)) * (1.0f / 9.0f));
        const float sorting = (gm9 - 5.0f) * 0.2f;

        // generalized mean p=10 over {5+5*macro, 5+5*sorting}
        const float c0 = fmaf(5.0f, macro_loss, 5.0f);
        const float c1 = fmaf(5.0f, sorting, 5.0f);
        const float a2 = c0 * c0, a4 = a2 * a2, a8 = a4 * a4;
        const float b2 = c1 * c1, b4 = b2 * b2, b8 = b4 * b4;
        const float m10 = (a8 * a2 + b8 * b2) * 0.5f;
        const float gm10 = exp2f(log2f(m10) * 0.1f);

        out[row] = (gm10 - 5.0f) * 0.2f;
    }
}

extern "C" void kernel_launch(void* const* d_in, const int* in_sizes, int n_in,
                              void* d_out, int out_size, void* d_ws, size_t ws_size,
                              hipStream_t stream) {
    const float* y_pred = (const float*)d_in[0];
    const int*   y_att  = (const int*)d_in[1];
    float* out = (float*)d_out;
    const int B = in_sizes[0] / NC;          // 32768
    const int blocks = (B + 3) / 4;          // 4 rows (waves) per block
    boiler_loss_kernel<<<blocks, 256, 0, stream>>>(y_pred, y_att, out, B);
}

// Round 3
// 183.852 us; speedup vs baseline: 1.0819x; 1.0003x over previous
//
#include <hip/hip_runtime.h>
#include <math.h>

// B=32768 rows, C=1000 classes, K=10 attack indices per row.
// One wave (64 lanes) per row; 4 waves per 256-thread block.
// Memory floor: 131 MB read -> ~20us at ~6.5 TB/s. Kernel is VALU-issue
// limited, so every wave-instruction in the common path counts.
//
// Key structure:
//  - softmax never materialized: row max m, S=sum(exp), 10 gathered logits,
//    and max over non-attack complement are sufficient (exp is monotone).
//  - mNA rare-path: if max(attack logits) < max(all) -- ~99% of rows, and
//    wave-uniform since 1 row == 1 wave -- then pNA = 1/S exactly; the
//    masked complement max runs only on ~1% of waves.
//  - epilogue parallelized across lanes (diffs on lanes 0..8, 16-group
//    butterflies), tiny serial tail on lane 0.
//  - fp32 throughout; x^(1/p) via exp2(log2(x)/p). abs err ~1e-5 vs 1.27e-3.

#define NC 1000
#define NK 10
#define NV4 250   // float4s per row; row stride 4000B is 16B-aligned
#define L2E 1.44269504088896340736f

#if __has_builtin(__builtin_amdgcn_exp2f)
#define EXP2F(x) __builtin_amdgcn_exp2f(x)
#else
#define EXP2F(x) exp2f(x)
#endif
#if __has_builtin(__builtin_amdgcn_logf)
#define LOG2F(x) __builtin_amdgcn_logf(x)
#else
#define LOG2F(x) log2f(x)
#endif
#if __has_builtin(__builtin_amdgcn_rcpf)
#define RCPF(x) __builtin_amdgcn_rcpf(x)
#else
#define RCPF(x) (1.0f / (x))
#endif

__global__ __launch_bounds__(256) void boiler_loss_kernel(
    const float* __restrict__ y_pred,
    const int*   __restrict__ y_att,
    float*       __restrict__ out,
    int B)
{
    const int wave = threadIdx.x >> 6;   // 0..3
    const int lane = threadIdx.x & 63;
    const int row  = blockIdx.x * 4 + wave;
    if (row >= B) return;

    const float* __restrict__ xrow = y_pred + (size_t)row * NC;
    const int*   __restrict__ arow = y_att + (size_t)row * NK;

    // per-lane attack index (lanes >= 10 duplicate index 9: harmless for
    // max-of-attack and min-of-attack-probs)
    const int aidx = arow[lane < NK ? lane : (NK - 1)];
    const float aval = xrow[aidx];                 // cache-hit gather

    // ---- main streaming load: 250 float4s, lane + 64*k ----
    float v[16];
    const float4* __restrict__ xv = (const float4*)xrow;
    #pragma unroll
    for (int k = 0; k < 4; ++k) {
        const int i4 = lane + 64 * k;
        float4 f;
        if (i4 < NV4) f = xv[i4];
        else f = make_float4(-INFINITY, -INFINITY, -INFINITY, -INFINITY);
        v[4*k+0] = f.x; v[4*k+1] = f.y; v[4*k+2] = f.z; v[4*k+3] = f.w;
    }

    // ---- row max (compiler fuses fmaxf chains into v_max3_f32) ----
    float mAll = fmaxf(fmaxf(fmaxf(v[0], v[1]), fmaxf(v[2], v[3])),
                       fmaxf(fmaxf(v[4], v[5]), fmaxf(v[6], v[7])));
    mAll = fmaxf(mAll,
                 fmaxf(fmaxf(fmaxf(v[8], v[9]), fmaxf(v[10], v[11])),
                       fmaxf(fmaxf(v[12], v[13]), fmaxf(v[14], v[15]))));
    float mAtt = aval;  // all 64 lanes hold an attack logit (with dups)
    #pragma unroll
    for (int off = 32; off > 0; off >>= 1) {
        mAll = fmaxf(mAll, __shfl_xor(mAll, off, 64));
        mAtt = fmaxf(mAtt, __shfl_xor(mAtt, off, 64));
    }

    // ---- sum of 2^((x-m)*log2e); padding lanes give exp2(-inf)=0 ----
    const float mscale = -mAll * L2E;
    float s = 0.0f;
    #pragma unroll
    for (int r = 0; r < 16; ++r) s += EXP2F(fmaf(v[r], L2E, mscale));
    #pragma unroll
    for (int off = 32; off > 0; off >>= 1) s += __shfl_xor(s, off, 64);

    const float rs = RCPF(s);

    // ---- pNA: max prob over the non-attack complement ----
    float pNA;
    if (mAtt < mAll) {
        // global argmax is NOT an attack element (wave-uniform, ~99% of rows)
        pNA = rs;                                   // exp(mAll-mAll)/S
    } else {
        // rare: build ownership mask and take the masked max.
        // element gi -> vec i4=gi>>2 -> lane=i4&63, reg=((i4>>6)<<2)|(gi&3)
        unsigned bits = 0u;
        #pragma unroll
        for (int j = 0; j < NK; ++j) {
            const int aj    = arow[j];              // wave-uniform -> s_load
            const int i4a   = aj >> 2;
            const int owner = i4a & 63;
            const int reg   = ((i4a >> 6) << 2) | (aj & 3);
            bits |= (owner == lane) ? (1u << reg) : 0u;
        }
        float mNA = -INFINITY;
        #pragma unroll
        for (int r = 0; r < 16; ++r)
            mNA = fmaxf(mNA, ((bits >> r) & 1u) ? -INFINITY : v[r]);
        #pragma unroll
        for (int off = 32; off > 0; off >>= 1)
            mNA = fmaxf(mNA, __shfl_xor(mNA, off, 64));
        pNA = EXP2F(fmaf(mNA, L2E, mscale)) * rs;
    }

    // ---- attack probs: lanes 0..9 hold p0..p9 (dups above) ----
    const float pj = EXP2F(fmaf(aval, L2E, mscale)) * rs;

    // pmin over attack set: dups are harmless for min; lanes 0..15 all
    // contain only attack probs, so a 16-group butterfly suffices.
    float pmin = pj;
    // 9th powers of (5 + 5*(p_{j+1}-p_j)) on lanes 0..8, zero elsewhere
    const float pnext = __shfl_down(pj, 1, 64);
    float t9;
    {
        const float sv = fmaf(5.0f, pnext - pj, 5.0f);   // in [0,10]
        const float x2 = sv * sv;
        const float x4 = x2 * x2;
        const float x8 = x4 * x4;
        t9 = (lane < NK - 1) ? x8 * sv : 0.0f;
    }
    #pragma unroll
    for (int off = 8; off > 0; off >>= 1) {
        pmin = fminf(pmin, __shfl_xor(pmin, off, 64));
        t9  += __shfl_xor(t9, off, 64);
    }

    if (lane == 0) {
        const float gm9 = EXP2F(LOG2F(t9 * (1.0f / 9.0f)) * (1.0f / 9.0f));
        const float sorting = (gm9 - 5.0f) * 0.2f;
        const float macro_loss = pNA - pmin;

        const float c0 = fmaf(5.0f, macro_loss, 5.0f);
        const float c1 = fmaf(5.0f, sorting, 5.0f);
        const float a2 = c0 * c0, a4 = a2 * a2, a8 = a4 * a4;
        const float b2 = c1 * c1, b4 = b2 * b2, b8 = b4 * b4;
        const float m10 = (a8 * a2 + b8 * b2) * 0.5f;
        const float gm10 = EXP2F(LOG2F(m10) * 0.1f);

        out[row] = (gm10 - 5.0f) * 0.2f;
    }
}

extern "C" void kernel_launch(void* const* d_in, const int* in_sizes, int n_in,
                              void* d_out, int out_size, void* d_ws, size_t ws_size,
                              hipStream_t stream) {
    const float* y_pred = (const float*)d_in[0];
    const int*   y_att  = (const int*)d_in[1];
    float* out = (float*)d_out;
    const int B = in_sizes[0] / NC;          // 32768
    const int blocks = (B + 3) / 4;          // 4 rows (waves) per block
    boiler_loss_kernel<<<blocks, 256, 0, stream>>>(y_pred, y_att, out, B);
}